// Round 1
// baseline (6906.911 us; speedup 1.0000x reference)
//
#include <hip/hip_runtime.h>
#include <cmath>

#define HIDDEN 256
#define NUM_REL 6
#define NUM_BASES 30

// ---------------- W[r] = sum_b att[r,b] * basis[b]  (r = 0..5) --------------
__global__ void compute_W_kernel(const float* __restrict__ att,
                                 const float* __restrict__ basis,
                                 float* __restrict__ W) {
  int idx = blockIdx.x * blockDim.x + threadIdx.x;   // over 6*65536
  int r  = idx >> 16;
  int io = idx & 65535;
  float s = 0.f;
#pragma unroll
  for (int b = 0; b < NUM_BASES; ++b)
    s += att[r * NUM_BASES + b] * basis[(size_t)b * 65536 + io];
  W[idx] = s;
}

// ---------------- fp32 tiled GEMM: C[M,256] = A[M,256] * B[256,256] ---------
// 64x64 tile, 256 threads, 4x4 accumulators per thread, BK=16.
__global__ __launch_bounds__(256) void gemm_f32(const float* __restrict__ A,
                                                const float* __restrict__ B,
                                                float* __restrict__ C, int M) {
  __shared__ float As[16][68];   // [k][m], pad: row stride 272B (16B aligned)
  __shared__ float Bs[16][64];   // [k][n]

  const int tid  = threadIdx.x;
  const int brow = blockIdx.x;
  const int bcol = blockIdx.y;
  const int tx = tid & 15, ty = tid >> 4;

  const int arow = tid >> 2, akq = tid & 3;   // A tile load mapping
  const int bk   = tid >> 4, bjq = tid & 15;  // B tile load mapping
  const int grow = brow * 64 + arow;

  const float* Aptr = A + (size_t)grow * 256 + akq * 4;
  const float* Bptr = B + (size_t)bk * 256 + bcol * 64 + bjq * 4;

  float acc[4][4] = {};

  for (int k0 = 0; k0 < 256; k0 += 16) {
    float4 av = make_float4(0.f, 0.f, 0.f, 0.f);
    if (grow < M) av = *(const float4*)(Aptr + k0);
    float4 bv = *(const float4*)(Bptr + (size_t)k0 * 256);

    As[akq * 4 + 0][arow] = av.x;
    As[akq * 4 + 1][arow] = av.y;
    As[akq * 4 + 2][arow] = av.z;
    As[akq * 4 + 3][arow] = av.w;
    *(float4*)&Bs[bk][bjq * 4] = bv;
    __syncthreads();

#pragma unroll
    for (int k = 0; k < 16; ++k) {
      float4 a = *(const float4*)&As[k][ty * 4];
      float4 b = *(const float4*)&Bs[k][tx * 4];
      acc[0][0] += a.x * b.x; acc[0][1] += a.x * b.y; acc[0][2] += a.x * b.z; acc[0][3] += a.x * b.w;
      acc[1][0] += a.y * b.x; acc[1][1] += a.y * b.y; acc[1][2] += a.y * b.z; acc[1][3] += a.y * b.w;
      acc[2][0] += a.z * b.x; acc[2][1] += a.z * b.y; acc[2][2] += a.z * b.z; acc[2][3] += a.z * b.w;
      acc[3][0] += a.w * b.x; acc[3][1] += a.w * b.y; acc[3][2] += a.w * b.z; acc[3][3] += a.w * b.w;
    }
    __syncthreads();
  }

  const int crow0 = brow * 64 + ty * 4;
  const int ccol  = bcol * 64 + tx * 4;
#pragma unroll
  for (int i = 0; i < 4; ++i) {
    if (crow0 + i < M) {
      float4 v = make_float4(acc[i][0], acc[i][1], acc[i][2], acc[i][3]);
      *(float4*)&C[(size_t)(crow0 + i) * 256 + ccol] = v;
    }
  }
}

// ---------------- degree: deg[dst] += 1 -------------------------------------
__global__ void deg_kernel(const int* __restrict__ dst, float* __restrict__ deg,
                           int E) {
  int stride = gridDim.x * blockDim.x;
  for (int e = blockIdx.x * blockDim.x + threadIdx.x; e < E; e += stride)
    unsafeAtomicAdd(&deg[dst[e]], 1.0f);
}

// ---------------- edge pass for relation r ----------------------------------
// one wave (64 lanes) per edge: gather msg, sigmoid gate, atomic scatter-add.
__global__ __launch_bounds__(256) void edge_pass(
    const float* __restrict__ xw, const int* __restrict__ src,
    const int* __restrict__ dst, const int* __restrict__ ety,
    const float* __restrict__ gate_w, const float* __restrict__ gate_b,
    float* __restrict__ agg, int E, int r) {
  const int lane  = threadIdx.x & 63;
  const int wave  = (blockIdx.x * blockDim.x + threadIdx.x) >> 6;
  const int nwav  = (gridDim.x * blockDim.x) >> 6;

  const float4 gw = ((const float4*)gate_w)[lane];
  const float  gb = gate_b[0];

  for (int e = wave; e < E; e += nwav) {
    if (ety[e] != r) continue;
    const float4 m = ((const float4*)(xw + (size_t)src[e] * HIDDEN))[lane];
    float dot = m.x * gw.x + m.y * gw.y + m.z * gw.z + m.w * gw.w;
#pragma unroll
    for (int off = 32; off; off >>= 1) dot += __shfl_xor(dot, off);
    const float g = 1.f / (1.f + expf(-(dot + gb)));
    float* a = agg + (size_t)dst[e] * HIDDEN + lane * 4;
    unsafeAtomicAdd(a + 0, g * m.x);
    unsafeAtomicAdd(a + 1, g * m.y);
    unsafeAtomicAdd(a + 2, g * m.z);
    unsafeAtomicAdd(a + 3, g * m.w);
  }
}

// ---------------- finalize: out = [relu](agg/max(deg,1) + xroot + bias) -----
__global__ void finalize_kernel(const float* __restrict__ agg,
                                const float* __restrict__ deg,
                                const float* __restrict__ xroot,
                                const float* __restrict__ bias,
                                float* __restrict__ out, int total, int relu) {
  int idx = blockIdx.x * blockDim.x + threadIdx.x;
  if (idx >= total) return;
  int n = idx >> 8;
  int j = idx & (HIDDEN - 1);
  float d = fmaxf(deg[n], 1.f);
  float v = agg[idx] / d + xroot[idx] + bias[j];
  out[idx] = relu ? fmaxf(v, 0.f) : v;
}

extern "C" void kernel_launch(void* const* d_in, const int* in_sizes, int n_in,
                              void* d_out, int out_size, void* d_ws,
                              size_t ws_size, hipStream_t stream) {
  const float* x    = (const float*)d_in[0];
  const int*   src  = (const int*)d_in[1];
  const int*   dst  = (const int*)d_in[2];
  const int*   ety  = (const int*)d_in[3];
  const float* basis1 = (const float*)d_in[4];
  const float* att1   = (const float*)d_in[5];
  const float* root1  = (const float*)d_in[6];
  const float* bias1  = (const float*)d_in[7];
  const float* gw1    = (const float*)d_in[8];
  const float* gb1    = (const float*)d_in[9];
  const float* basis2 = (const float*)d_in[10];
  const float* att2   = (const float*)d_in[11];
  const float* root2  = (const float*)d_in[12];
  const float* bias2  = (const float*)d_in[13];
  const float* gw2    = (const float*)d_in[14];
  const float* gb2    = (const float*)d_in[15];

  const int N = in_sizes[0] / HIDDEN;   // 50000
  const int E = in_sizes[1];            // 800000

  float* ws   = (float*)d_ws;
  float* W    = ws;                        // 6*65536
  float* xw   = W + NUM_REL * 65536;       // N*256
  float* agg  = xw + (size_t)N * HIDDEN;   // N*256
  float* h    = agg + (size_t)N * HIDDEN;  // N*256
  float* deg  = h + (size_t)N * HIDDEN;    // N

  // degree (identical for both layers)
  hipMemsetAsync(deg, 0, (size_t)N * sizeof(float), stream);
  deg_kernel<<<2048, 256, 0, stream>>>(dst, deg, E);

  const dim3 ggrid((N + 63) / 64, 4);

  for (int layer = 0; layer < 2; ++layer) {
    const float* in   = layer ? h : x;
    const float* bas  = layer ? basis2 : basis1;
    const float* att  = layer ? att2 : att1;
    const float* root = layer ? root2 : root1;
    const float* bias = layer ? bias2 : bias1;
    const float* gw   = layer ? gw2 : gw1;
    const float* gb   = layer ? gb2 : gb1;
    float* outbuf     = layer ? (float*)d_out : h;

    hipMemsetAsync(agg, 0, (size_t)N * HIDDEN * sizeof(float), stream);
    compute_W_kernel<<<NUM_REL * 65536 / 256, 256, 0, stream>>>(att, bas, W);

    for (int r = 0; r < NUM_REL; ++r) {
      gemm_f32<<<ggrid, 256, 0, stream>>>(in, W + (size_t)r * 65536, xw, N);
      edge_pass<<<4096, 256, 0, stream>>>(xw, src, dst, ety, gw, gb, agg, E, r);
    }
    // root term into d_out (scratch in layer 0; final residence in layer 1)
    gemm_f32<<<ggrid, 256, 0, stream>>>(in, root, (float*)d_out, N);

    finalize_kernel<<<(N * HIDDEN + 255) / 256, 256, 0, stream>>>(
        agg, deg, (const float*)d_out, bias, outbuf, (int)N * HIDDEN,
        layer == 0 ? 1 : 0);
  }
}

// Round 2
// 1969.971 us; speedup vs baseline: 3.5061x; 3.5061x over previous
//
#include <hip/hip_runtime.h>
#include <cmath>

#define HIDDEN 256
#define NUM_REL 6

// ---------------- W[r] = sum_b att[r,b] * basis[b]  (r = 0..5) --------------
__global__ void compute_W_kernel(const float* __restrict__ att,
                                 const float* __restrict__ basis,
                                 float* __restrict__ W) {
  int idx = blockIdx.x * blockDim.x + threadIdx.x;   // over 6*65536
  int r  = idx >> 16;
  int io = idx & 65535;
  float s = 0.f;
#pragma unroll
  for (int b = 0; b < 30; ++b)
    s += att[r * 30 + b] * basis[(size_t)b * 65536 + io];
  W[idx] = s;
}

// ---------------- fp32 tiled GEMM: C[M,256] = A[M,256] * B[256,256] ---------
__global__ __launch_bounds__(256) void gemm_f32(const float* __restrict__ A,
                                                const float* __restrict__ B,
                                                float* __restrict__ C, int M) {
  __shared__ float As[16][68];
  __shared__ float Bs[16][64];

  const int tid  = threadIdx.x;
  const int brow = blockIdx.x;
  const int bcol = blockIdx.y;
  const int tx = tid & 15, ty = tid >> 4;

  const int arow = tid >> 2, akq = tid & 3;
  const int bk   = tid >> 4, bjq = tid & 15;
  const int grow = brow * 64 + arow;

  const float* Aptr = A + (size_t)grow * 256 + akq * 4;
  const float* Bptr = B + (size_t)bk * 256 + bcol * 64 + bjq * 4;

  float acc[4][4] = {};

  for (int k0 = 0; k0 < 256; k0 += 16) {
    float4 av = make_float4(0.f, 0.f, 0.f, 0.f);
    if (grow < M) av = *(const float4*)(Aptr + k0);
    float4 bv = *(const float4*)(Bptr + (size_t)k0 * 256);

    As[akq * 4 + 0][arow] = av.x;
    As[akq * 4 + 1][arow] = av.y;
    As[akq * 4 + 2][arow] = av.z;
    As[akq * 4 + 3][arow] = av.w;
    *(float4*)&Bs[bk][bjq * 4] = bv;
    __syncthreads();

#pragma unroll
    for (int k = 0; k < 16; ++k) {
      float4 a = *(const float4*)&As[k][ty * 4];
      float4 b = *(const float4*)&Bs[k][tx * 4];
      acc[0][0] += a.x * b.x; acc[0][1] += a.x * b.y; acc[0][2] += a.x * b.z; acc[0][3] += a.x * b.w;
      acc[1][0] += a.y * b.x; acc[1][1] += a.y * b.y; acc[1][2] += a.y * b.z; acc[1][3] += a.y * b.w;
      acc[2][0] += a.z * b.x; acc[2][1] += a.z * b.y; acc[2][2] += a.z * b.z; acc[2][3] += a.z * b.w;
      acc[3][0] += a.w * b.x; acc[3][1] += a.w * b.y; acc[3][2] += a.w * b.z; acc[3][3] += a.w * b.w;
    }
    __syncthreads();
  }

  const int crow0 = brow * 64 + ty * 4;
  const int ccol  = bcol * 64 + tx * 4;
#pragma unroll
  for (int i = 0; i < 4; ++i) {
    if (crow0 + i < M) {
      float4 v = make_float4(acc[i][0], acc[i][1], acc[i][2], acc[i][3]);
      *(float4*)&C[(size_t)(crow0 + i) * 256 + ccol] = v;
    }
  }
}

// ---------------- CSR build: histogram over (rel,dst) bins ------------------
__global__ void hist_kernel(const int* __restrict__ dst,
                            const int* __restrict__ ety,
                            int* __restrict__ cnt, int E, int N) {
  int stride = gridDim.x * blockDim.x;
  for (int e = blockIdx.x * blockDim.x + threadIdx.x; e < E; e += stride)
    atomicAdd(&cnt[ety[e] * N + dst[e]], 1);
}

// exclusive scan over n ints: 3 kernels, 1024 elems/block
__global__ void scan_reduce(const int* __restrict__ cnt,
                            int* __restrict__ blockSums, int n) {
  __shared__ int sd[256];
  int base = blockIdx.x * 1024;
  int t = threadIdx.x;
  int s = 0;
#pragma unroll
  for (int i = 0; i < 4; ++i) {
    int idx = base + t * 4 + i;
    s += (idx < n) ? cnt[idx] : 0;
  }
  sd[t] = s; __syncthreads();
  for (int off = 128; off; off >>= 1) {
    if (t < off) sd[t] += sd[t + off];
    __syncthreads();
  }
  if (t == 0) blockSums[blockIdx.x] = sd[0];
}

__global__ void scan_offsets(int* __restrict__ blockSums, int nb) {
  if (threadIdx.x == 0 && blockIdx.x == 0) {
    int run = 0;
    for (int i = 0; i < nb; ++i) { int v = blockSums[i]; blockSums[i] = run; run += v; }
  }
}

__global__ void scan_write(const int* __restrict__ cnt,
                           const int* __restrict__ blockSums,
                           int* __restrict__ row_ptr, int n) {
  __shared__ int sd[256];
  int base = blockIdx.x * 1024;
  int t = threadIdx.x;
  int v[4]; int s = 0;
#pragma unroll
  for (int i = 0; i < 4; ++i) {
    int idx = base + t * 4 + i;
    v[i] = (idx < n) ? cnt[idx] : 0;
    s += v[i];
  }
  sd[t] = s; __syncthreads();
  for (int off = 1; off < 256; off <<= 1) {
    int val = (t >= off) ? sd[t - off] : 0;
    __syncthreads();
    sd[t] += val;
    __syncthreads();
  }
  int excl = blockSums[blockIdx.x] + sd[t] - s;   // exclusive thread offset
  for (int i = 0; i < 4; ++i) {
    int idx = base + t * 4 + i;
    if (idx < n) {
      row_ptr[idx] = excl;
      excl += v[i];
      if (idx == n - 1) row_ptr[n] = excl;
    }
  }
}

__global__ void scatter_kernel(const int* __restrict__ src,
                               const int* __restrict__ dst,
                               const int* __restrict__ ety,
                               int* __restrict__ cursor,
                               int* __restrict__ src_s, int E, int N) {
  int stride = gridDim.x * blockDim.x;
  for (int e = blockIdx.x * blockDim.x + threadIdx.x; e < E; e += stride) {
    int bin = ety[e] * N + dst[e];
    int pos = atomicAdd(&cursor[bin], 1);
    src_s[pos] = src[e];
  }
}

__global__ void deg_from_csr(const int* __restrict__ row_ptr,
                             float* __restrict__ deg, int N) {
  int n = blockIdx.x * blockDim.x + threadIdx.x;
  if (n >= N) return;
  int d = 0;
#pragma unroll
  for (int r = 0; r < NUM_REL; ++r)
    d += row_ptr[r * N + n + 1] - row_ptr[r * N + n];
  deg[n] = (float)d;
}

// ---------------- atomic-free aggregation: one wave per dst node ------------
__global__ __launch_bounds__(256) void agg_pass(
    const float* __restrict__ xw, const int* __restrict__ row_ptr,
    const int* __restrict__ src_s, const float* __restrict__ gate_w,
    const float* __restrict__ gate_b, float* __restrict__ agg, int N, int r) {
  const int wave = (blockIdx.x * blockDim.x + threadIdx.x) >> 6;
  if (wave >= N) return;
  const int lane = threadIdx.x & 63;
  const int bin  = r * N + wave;
  const int beg = row_ptr[bin], end = row_ptr[bin + 1];
  if (beg == end) return;

  const float4 gw = ((const float4*)gate_w)[lane];
  const float  gb = gate_b[0];
  float4 acc = make_float4(0.f, 0.f, 0.f, 0.f);

  for (int e = beg; e < end; ++e) {
    const int s = src_s[e];
    const float4 m = ((const float4*)(xw + (size_t)s * HIDDEN))[lane];
    float dot = m.x * gw.x + m.y * gw.y + m.z * gw.z + m.w * gw.w;
#pragma unroll
    for (int off = 32; off; off >>= 1) dot += __shfl_xor(dot, off);
    const float g = 1.f / (1.f + __expf(-(dot + gb)));
    acc.x += g * m.x; acc.y += g * m.y; acc.z += g * m.z; acc.w += g * m.w;
  }

  float* a = agg + (size_t)wave * HIDDEN + lane * 4;
  float4 cur = *(const float4*)a;
  cur.x += acc.x; cur.y += acc.y; cur.z += acc.z; cur.w += acc.w;
  *(float4*)a = cur;
}

// ---------------- finalize: out = [relu](agg/max(deg,1) + xroot + bias) -----
__global__ void finalize_kernel(const float* __restrict__ agg,
                                const float* __restrict__ deg,
                                const float* __restrict__ xroot,
                                const float* __restrict__ bias,
                                float* __restrict__ out, int total, int relu) {
  int idx = blockIdx.x * blockDim.x + threadIdx.x;
  if (idx >= total) return;
  int n = idx >> 8;
  int j = idx & (HIDDEN - 1);
  float d = fmaxf(deg[n], 1.f);
  float v = agg[idx] / d + xroot[idx] + bias[j];
  out[idx] = relu ? fmaxf(v, 0.f) : v;
}

extern "C" void kernel_launch(void* const* d_in, const int* in_sizes, int n_in,
                              void* d_out, int out_size, void* d_ws,
                              size_t ws_size, hipStream_t stream) {
  const float* x    = (const float*)d_in[0];
  const int*   src  = (const int*)d_in[1];
  const int*   dst  = (const int*)d_in[2];
  const int*   ety  = (const int*)d_in[3];
  const float* basis1 = (const float*)d_in[4];
  const float* att1   = (const float*)d_in[5];
  const float* root1  = (const float*)d_in[6];
  const float* bias1  = (const float*)d_in[7];
  const float* gw1    = (const float*)d_in[8];
  const float* gb1    = (const float*)d_in[9];
  const float* basis2 = (const float*)d_in[10];
  const float* att2   = (const float*)d_in[11];
  const float* root2  = (const float*)d_in[12];
  const float* bias2  = (const float*)d_in[13];
  const float* gw2    = (const float*)d_in[14];
  const float* gb2    = (const float*)d_in[15];

  const int N  = in_sizes[0] / HIDDEN;   // 50000
  const int E  = in_sizes[1];            // 800000
  const int RN = NUM_REL * N;            // 300000

  // ---- workspace layout (4-byte units, all 16B-aligned sizes) ----
  float* ws  = (float*)d_ws;
  float* W   = ws;                               // 6*65536
  float* xw  = W + NUM_REL * 65536;              // N*256
  float* agg = xw + (size_t)N * HIDDEN;          // N*256
  float* h   = agg + (size_t)N * HIDDEN;         // N*256
  float* deg = h + (size_t)N * HIDDEN;           // N (50000, 16B-mult)
  int* cnt      = (int*)(deg + N);               // RN
  int* cursor   = cnt + RN;                      // RN
  int* row_ptr  = cursor + RN;                   // RN+1 (pad to RN+4)
  int* blockSums= row_ptr + RN + 4;              // <=512
  int* src_s    = blockSums + 512;               // E

  const int scanBlocks = (RN + 1023) / 1024;

  // ---- CSR build (once; shared by both layers) ----
  hipMemsetAsync(cnt, 0, (size_t)RN * sizeof(int), stream);
  hist_kernel<<<2048, 256, 0, stream>>>(dst, ety, cnt, E, N);
  scan_reduce<<<scanBlocks, 256, 0, stream>>>(cnt, blockSums, RN);
  scan_offsets<<<1, 64, 0, stream>>>(blockSums, scanBlocks);
  scan_write<<<scanBlocks, 256, 0, stream>>>(cnt, blockSums, row_ptr, RN);
  hipMemcpyAsync(cursor, row_ptr, (size_t)RN * sizeof(int),
                 hipMemcpyDeviceToDevice, stream);
  scatter_kernel<<<2048, 256, 0, stream>>>(src, dst, ety, cursor, src_s, E, N);
  deg_from_csr<<<(N + 255) / 256, 256, 0, stream>>>(row_ptr, deg, N);

  const dim3 ggrid((N + 63) / 64, 4);
  const int aggBlocks = (N * 64 + 255) / 256;

  for (int layer = 0; layer < 2; ++layer) {
    const float* in   = layer ? h : x;
    const float* bas  = layer ? basis2 : basis1;
    const float* att  = layer ? att2 : att1;
    const float* root = layer ? root2 : root1;
    const float* bias = layer ? bias2 : bias1;
    const float* gw   = layer ? gw2 : gw1;
    const float* gb   = layer ? gb2 : gb1;
    float* outbuf     = layer ? (float*)d_out : h;

    hipMemsetAsync(agg, 0, (size_t)N * HIDDEN * sizeof(float), stream);
    compute_W_kernel<<<NUM_REL * 65536 / 256, 256, 0, stream>>>(att, bas, W);

    for (int r = 0; r < NUM_REL; ++r) {
      gemm_f32<<<ggrid, 256, 0, stream>>>(in, W + (size_t)r * 65536, xw, N);
      agg_pass<<<aggBlocks, 256, 0, stream>>>(xw, row_ptr, src_s, gw, gb, agg,
                                              N, r);
    }
    gemm_f32<<<ggrid, 256, 0, stream>>>(in, root, (float*)d_out, N);

    finalize_kernel<<<(N * HIDDEN + 255) / 256, 256, 0, stream>>>(
        agg, deg, (const float*)d_out, bias, outbuf, N * HIDDEN,
        layer == 0 ? 1 : 0);
  }
}

// Round 3
// 650.951 us; speedup vs baseline: 10.6105x; 3.0263x over previous
//
#include <hip/hip_runtime.h>
#include <cmath>

#define HIDDEN 256
#define NUM_REL 6

typedef float f32x4_t __attribute__((ext_vector_type(4)));
typedef short bf16x8_t __attribute__((ext_vector_type(8)));

__device__ __forceinline__ float bf2f(ushort u) {
  return __uint_as_float(((uint)u) << 16);
}
__device__ __forceinline__ ushort f2bf(float f) {
  uint u = __float_as_uint(f);
  u += 0x7FFFu + ((u >> 16) & 1u);
  return (ushort)(u >> 16);
}

// ---------------- Wall[r][k][o] = sum_b att[r,b] * basis[b][k][o] -----------
__global__ void compute_W_kernel(const float* __restrict__ att,
                                 const float* __restrict__ basis,
                                 float* __restrict__ Wall) {
  int idx = blockIdx.x * blockDim.x + threadIdx.x;   // over 6*65536
  int r  = idx >> 16;
  int io = idx & 65535;
  float s = 0.f;
#pragma unroll
  for (int b = 0; b < 30; ++b)
    s += att[r * 30 + b] * basis[(size_t)b * 65536 + io];
  Wall[idx] = s;
}

// ---------------- B_T[n][k] bf16, n = r*256+o (r=6 -> root) -----------------
__global__ __launch_bounds__(256) void build_BT(const float* __restrict__ Wall,
                                                const float* __restrict__ root,
                                                ushort* __restrict__ BT) {
  __shared__ float t[64][65];
  const int o0 = blockIdx.x * 64, k0 = blockIdx.y * 64, r = blockIdx.z;
  const float* S = (r < 6) ? (Wall + (size_t)r * 65536) : root;
  const int tx = threadIdx.x & 63, ty = threadIdx.x >> 6;
  for (int kk = ty; kk < 64; kk += 4)
    t[kk][tx] = S[(size_t)(k0 + kk) * 256 + o0 + tx];
  __syncthreads();
  for (int oo = ty; oo < 64; oo += 4)
    BT[(size_t)(r * 256 + o0 + oo) * 256 + k0 + tx] = f2bf(t[tx][oo]);
}

// ---------------- fp32 -> bf16 convert --------------------------------------
__global__ void cvt_f32_bf16(const float* __restrict__ in,
                             ushort* __restrict__ out, int n4) {
  int i = blockIdx.x * blockDim.x + threadIdx.x;
  if (i >= n4) return;
  float4 v = ((const float4*)in)[i];
  ushort4 o;
  o.x = f2bf(v.x); o.y = f2bf(v.y); o.z = f2bf(v.z); o.w = f2bf(v.w);
  ((ushort4*)out)[i] = o;
}

// ---------------- bf16 MFMA GEMM: C[M,ncols] = A[M,256] * BT[n0+ncols,256]^T
// 128x128 tile, BK=64, 4 waves (2x2), 16x16x32 MFMA, swizzled LDS.
__global__ __launch_bounds__(256) void gemm_bf16(const ushort* __restrict__ A,
                                                 const ushort* __restrict__ BT,
                                                 ushort* __restrict__ C, int M,
                                                 int n0, int ncols) {
  __shared__ ushort As[128 * 64];
  __shared__ ushort Bs[128 * 64];
  const int tid = threadIdx.x;
  const int w = tid >> 6, l = tid & 63;
  const int wm = w & 1, wn = w >> 1;
  const int row0 = blockIdx.x * 128;
  const int col0 = blockIdx.y * 128;

  const int srow = l >> 3;             // 0..7 within 8-row stage group
  const int schunk = (l & 7) ^ srow;   // pre-swizzled source chunk

  f32x4_t acc[4][4] = {};

  for (int k0 = 0; k0 < 256; k0 += 64) {
    if (k0) __syncthreads();
#pragma unroll
    for (int i = 0; i < 4; ++i) {
      const int br = (w * 4 + i) * 8;
      const int ga = min(row0 + br + srow, M - 1);
      const ushort* gp = A + (size_t)ga * 256 + k0 + schunk * 8;
      __builtin_amdgcn_global_load_lds(
          (const __attribute__((address_space(1))) void*)gp,
          (__attribute__((address_space(3))) void*)(As + br * 64), 16, 0, 0);
    }
#pragma unroll
    for (int i = 0; i < 4; ++i) {
      const int br = (w * 4 + i) * 8;
      const int gb = n0 + col0 + br + srow;
      const ushort* gp = BT + (size_t)gb * 256 + k0 + schunk * 8;
      __builtin_amdgcn_global_load_lds(
          (const __attribute__((address_space(1))) void*)gp,
          (__attribute__((address_space(3))) void*)(Bs + br * 64), 16, 0, 0);
    }
    __syncthreads();
#pragma unroll
    for (int kk = 0; kk < 2; ++kk) {
      const int swc = (kk * 4 + (l >> 4)) ^ (l & 7);
      bf16x8_t a[4], b[4];
#pragma unroll
      for (int m = 0; m < 4; ++m) {
        const int r = wm * 64 + m * 16 + (l & 15);
        a[m] = *(const bf16x8_t*)(As + r * 64 + swc * 8);
      }
#pragma unroll
      for (int n = 0; n < 4; ++n) {
        const int r = wn * 64 + n * 16 + (l & 15);
        b[n] = *(const bf16x8_t*)(Bs + r * 64 + swc * 8);
      }
#pragma unroll
      for (int m = 0; m < 4; ++m)
#pragma unroll
        for (int n = 0; n < 4; ++n)
          acc[m][n] = __builtin_amdgcn_mfma_f32_16x16x32_bf16(
              a[m], b[n], acc[m][n], 0, 0, 0);
    }
  }

  const int rbase = row0 + wm * 64 + (l >> 4) * 4;
  const int cbase = col0 + wn * 64 + (l & 15);
#pragma unroll
  for (int m = 0; m < 4; ++m)
#pragma unroll
    for (int n = 0; n < 4; ++n)
#pragma unroll
      for (int i = 0; i < 4; ++i) {
        const int row = rbase + m * 16 + i;
        if (row < M)
          C[(size_t)row * ncols + cbase + n * 16] = f2bf(acc[m][n][i]);
      }
}

// ---------------- CSR build -------------------------------------------------
__global__ void hist_kernel(const int* __restrict__ dst,
                            const int* __restrict__ ety,
                            int* __restrict__ cnt, int E, int N) {
  int stride = gridDim.x * blockDim.x;
  for (int e = blockIdx.x * blockDim.x + threadIdx.x; e < E; e += stride)
    atomicAdd(&cnt[ety[e] * N + dst[e]], 1);
}

__global__ void scan_reduce(const int* __restrict__ cnt,
                            int* __restrict__ blockSums, int n) {
  __shared__ int sd[256];
  int base = blockIdx.x * 1024;
  int t = threadIdx.x;
  int s = 0;
#pragma unroll
  for (int i = 0; i < 4; ++i) {
    int idx = base + t * 4 + i;
    s += (idx < n) ? cnt[idx] : 0;
  }
  sd[t] = s; __syncthreads();
  for (int off = 128; off; off >>= 1) {
    if (t < off) sd[t] += sd[t + off];
    __syncthreads();
  }
  if (t == 0) blockSums[blockIdx.x] = sd[0];
}

__global__ void scan_offsets(int* __restrict__ blockSums, int nb) {
  if (threadIdx.x == 0 && blockIdx.x == 0) {
    int run = 0;
    for (int i = 0; i < nb; ++i) { int v = blockSums[i]; blockSums[i] = run; run += v; }
  }
}

__global__ void scan_write(const int* __restrict__ cnt,
                           const int* __restrict__ blockSums,
                           int* __restrict__ row_ptr, int n) {
  __shared__ int sd[256];
  int base = blockIdx.x * 1024;
  int t = threadIdx.x;
  int v[4]; int s = 0;
#pragma unroll
  for (int i = 0; i < 4; ++i) {
    int idx = base + t * 4 + i;
    v[i] = (idx < n) ? cnt[idx] : 0;
    s += v[i];
  }
  sd[t] = s; __syncthreads();
  for (int off = 1; off < 256; off <<= 1) {
    int val = (t >= off) ? sd[t - off] : 0;
    __syncthreads();
    sd[t] += val;
    __syncthreads();
  }
  int excl = blockSums[blockIdx.x] + sd[t] - s;
  for (int i = 0; i < 4; ++i) {
    int idx = base + t * 4 + i;
    if (idx < n) {
      row_ptr[idx] = excl;
      excl += v[i];
      if (idx == n - 1) row_ptr[n] = excl;
    }
  }
}

__global__ void scatter_kernel(const int* __restrict__ src,
                               const int* __restrict__ dst,
                               const int* __restrict__ ety,
                               int* __restrict__ cursor,
                               int* __restrict__ src_s, int E, int N) {
  int stride = gridDim.x * blockDim.x;
  for (int e = blockIdx.x * blockDim.x + threadIdx.x; e < E; e += stride) {
    int bin = ety[e] * N + dst[e];
    int pos = atomicAdd(&cursor[bin], 1);
    src_s[pos] = src[e];
  }
}

__global__ void deg_from_csr(const int* __restrict__ row_ptr,
                             float* __restrict__ deg, int N) {
  int n = blockIdx.x * blockDim.x + threadIdx.x;
  if (n >= N) return;
  int d = 0;
#pragma unroll
  for (int r = 0; r < NUM_REL; ++r)
    d += row_ptr[r * N + n + 1] - row_ptr[r * N + n];
  deg[n] = (float)d;
}

// ---------------- gather + gate + aggregate (+ optional fused finalize) -----
// one wave per dst node. mode: 0 = RMW into agg, 1 = write agg, 2 = fused
// finalize (no agg buffer; reads root block of C at rootOff, writes output).
__global__ __launch_bounds__(256) void agg_kernel(
    const ushort* __restrict__ C, int ncols, int rbin0, int nrel, int rootOff,
    const int* __restrict__ row_ptr, const int* __restrict__ src_s,
    const float* __restrict__ gate_w, const float* __restrict__ gate_b,
    float* __restrict__ agg, const float* __restrict__ deg,
    const float* __restrict__ bias, void* __restrict__ outPtr, int outBf16,
    int relu, int N, int mode) {
  const int wave = (blockIdx.x * blockDim.x + threadIdx.x) >> 6;
  if (wave >= N) return;
  const int l = threadIdx.x & 63;
  const float4 gw = ((const float4*)gate_w)[l];
  const float gb = gate_b[0];
  float ax = 0.f, ay = 0.f, az = 0.f, aw = 0.f;

  for (int rr = 0; rr < nrel; ++rr) {
    const int bin = (rbin0 + rr) * N + wave;
    const int e1 = row_ptr[bin + 1];
    const ushort* Cr = C + (size_t)rr * 256 + l * 4;
    for (int e = row_ptr[bin]; e < e1; ++e) {
      const int s = src_s[e];
      const ushort4 mv = *(const ushort4*)(Cr + (size_t)s * ncols);
      const float m0 = bf2f(mv.x), m1 = bf2f(mv.y);
      const float m2 = bf2f(mv.z), m3 = bf2f(mv.w);
      float dot = m0 * gw.x + m1 * gw.y + m2 * gw.z + m3 * gw.w;
#pragma unroll
      for (int off = 32; off; off >>= 1) dot += __shfl_xor(dot, off);
      const float g = 1.f / (1.f + __expf(-(dot + gb)));
      ax += g * m0; ay += g * m1; az += g * m2; aw += g * m3;
    }
  }

  if (mode == 2) {
    const float d = fmaxf(deg[wave], 1.f);
    const ushort4 rv =
        *(const ushort4*)(C + (size_t)wave * ncols + rootOff + l * 4);
    const float4 bv = ((const float4*)bias)[l];
    float o0 = ax / d + bf2f(rv.x) + bv.x;
    float o1 = ay / d + bf2f(rv.y) + bv.y;
    float o2 = az / d + bf2f(rv.z) + bv.z;
    float o3 = aw / d + bf2f(rv.w) + bv.w;
    if (relu) {
      o0 = fmaxf(o0, 0.f); o1 = fmaxf(o1, 0.f);
      o2 = fmaxf(o2, 0.f); o3 = fmaxf(o3, 0.f);
    }
    if (outBf16) {
      ushort4 o;
      o.x = f2bf(o0); o.y = f2bf(o1); o.z = f2bf(o2); o.w = f2bf(o3);
      ((ushort4*)outPtr)[(size_t)wave * 64 + l] = o;
    } else {
      ((float4*)outPtr)[(size_t)wave * 64 + l] = make_float4(o0, o1, o2, o3);
    }
  } else {
    float* ap = agg + (size_t)wave * HIDDEN + l * 4;
    if (mode == 0) {
      float4 cur = *(const float4*)ap;
      ax += cur.x; ay += cur.y; az += cur.z; aw += cur.w;
    }
    *(float4*)ap = make_float4(ax, ay, az, aw);
  }
}

// ---------------- tier-B finalize: out = [relu](agg/deg + rootC + bias) -----
__global__ void finalize2(const float* __restrict__ agg,
                          const float* __restrict__ deg,
                          const ushort* __restrict__ Croot,
                          const float* __restrict__ bias,
                          void* __restrict__ outPtr, int outBf16, int relu,
                          int N) {
  int t = blockIdx.x * blockDim.x + threadIdx.x;
  if (t >= N * 64) return;
  int n = t >> 6, l = t & 63;
  float d = fmaxf(deg[n], 1.f);
  float4 a = ((const float4*)agg)[t];
  ushort4 rv = ((const ushort4*)Croot)[t];
  float4 bv = ((const float4*)bias)[l];
  float o0 = a.x / d + bf2f(rv.x) + bv.x;
  float o1 = a.y / d + bf2f(rv.y) + bv.y;
  float o2 = a.z / d + bf2f(rv.z) + bv.z;
  float o3 = a.w / d + bf2f(rv.w) + bv.w;
  if (relu) {
    o0 = fmaxf(o0, 0.f); o1 = fmaxf(o1, 0.f);
    o2 = fmaxf(o2, 0.f); o3 = fmaxf(o3, 0.f);
  }
  if (outBf16) {
    ushort4 o;
    o.x = f2bf(o0); o.y = f2bf(o1); o.z = f2bf(o2); o.w = f2bf(o3);
    ((ushort4*)outPtr)[t] = o;
  } else {
    ((float4*)outPtr)[t] = make_float4(o0, o1, o2, o3);
  }
}

static inline size_t align16(size_t x) { return (x + 15) & ~(size_t)15; }

extern "C" void kernel_launch(void* const* d_in, const int* in_sizes, int n_in,
                              void* d_out, int out_size, void* d_ws,
                              size_t ws_size, hipStream_t stream) {
  const float* x    = (const float*)d_in[0];
  const int*   src  = (const int*)d_in[1];
  const int*   dst  = (const int*)d_in[2];
  const int*   ety  = (const int*)d_in[3];

  const int N  = in_sizes[0] / HIDDEN;   // 50000
  const int E  = in_sizes[1];            // 800000
  const int RN = NUM_REL * N;

  // ---- workspace layout ----
  char* p = (char*)d_ws;
  float* Wall = (float*)p;  p += align16((size_t)NUM_REL * 65536 * 4);
  ushort* BT  = (ushort*)p; p += align16((size_t)1792 * 256 * 2);
  ushort* xb  = (ushort*)p; p += align16((size_t)N * HIDDEN * 2);   // x/h bf16
  float* agg  = (float*)p;  p += align16((size_t)N * HIDDEN * 4);
  float* deg  = (float*)p;  p += align16((size_t)N * 4);
  int* cnt       = (int*)p; p += align16((size_t)RN * 4);
  int* cursor    = (int*)p; p += align16((size_t)RN * 4);
  int* row_ptr   = (int*)p; p += align16((size_t)(RN + 1) * 4);
  int* blockSums = (int*)p; p += 2048;
  int* src_s     = (int*)p; p += align16((size_t)E * 4);
  ushort* C      = (ushort*)p;
  const size_t fixedBytes = (size_t)(p - (char*)d_ws);
  const bool tierA = ws_size >= fixedBytes + (size_t)N * 1792 * 2;

  const int scanBlocks = (RN + 1023) / 1024;

  // ---- CSR build (shared by both layers) ----
  hipMemsetAsync(cnt, 0, (size_t)RN * sizeof(int), stream);
  hist_kernel<<<2048, 256, 0, stream>>>(dst, ety, cnt, E, N);
  scan_reduce<<<scanBlocks, 256, 0, stream>>>(cnt, blockSums, RN);
  scan_offsets<<<1, 64, 0, stream>>>(blockSums, scanBlocks);
  scan_write<<<scanBlocks, 256, 0, stream>>>(cnt, blockSums, row_ptr, RN);
  hipMemcpyAsync(cursor, row_ptr, (size_t)RN * sizeof(int),
                 hipMemcpyDeviceToDevice, stream);
  scatter_kernel<<<2048, 256, 0, stream>>>(src, dst, ety, cursor, src_s, E, N);
  deg_from_csr<<<(N + 255) / 256, 256, 0, stream>>>(row_ptr, deg, N);

  // x -> bf16
  cvt_f32_bf16<<<(N * 64 + 255) / 256, 256, 0, stream>>>(x, xb, N * 64);

  const int aggBlocks = (N * 64 + 255) / 256;
  const int mBlocks = (N + 127) / 128;

  for (int layer = 0; layer < 2; ++layer) {
    const float* bas  = (const float*)d_in[layer ? 10 : 4];
    const float* att  = (const float*)d_in[layer ? 11 : 5];
    const float* root = (const float*)d_in[layer ? 12 : 6];
    const float* bias = (const float*)d_in[layer ? 13 : 7];
    const float* gw   = (const float*)d_in[layer ? 14 : 8];
    const float* gb   = (const float*)d_in[layer ? 15 : 9];
    void* outp  = layer ? d_out : (void*)xb;   // layer0 writes h (bf16) in-place
    const int outBf16 = layer ? 0 : 1;
    const int relu    = layer ? 0 : 1;

    compute_W_kernel<<<NUM_REL * 65536 / 256, 256, 0, stream>>>(att, bas, Wall);
    build_BT<<<dim3(4, 4, 7), 256, 0, stream>>>(Wall, root, BT);

    if (tierA) {
      gemm_bf16<<<dim3(mBlocks, 14), 256, 0, stream>>>(xb, BT, C, N, 0, 1792);
      agg_kernel<<<aggBlocks, 256, 0, stream>>>(
          C, 1792, 0, NUM_REL, 1536, row_ptr, src_s, gw, gb, agg, deg, bias,
          outp, outBf16, relu, N, 2);
    } else {
      for (int r = 0; r < NUM_REL; ++r) {
        gemm_bf16<<<dim3(mBlocks, 2), 256, 0, stream>>>(xb, BT, C, N, r * 256,
                                                        256);
        agg_kernel<<<aggBlocks, 256, 0, stream>>>(
            C, 256, r, 1, 0, row_ptr, src_s, gw, gb, agg, deg, bias, nullptr,
            0, 0, N, r == 0 ? 1 : 0);
      }
      gemm_bf16<<<dim3(mBlocks, 2), 256, 0, stream>>>(xb, BT, C, N, 1536, 256);
      finalize2<<<aggBlocks, 256, 0, stream>>>(agg, deg, C, bias, outp,
                                               outBf16, relu, N);
    }
  }
}